// Round 3
// baseline (226.358 us; speedup 1.0000x reference)
//
#include <hip/hip_runtime.h>

#define B_ 2
#define T_ 2048
#define C_ 1024
#define H_ 16
#define D_ 64
#define M_ (B_ * T_)       // 4096 rows
#define NQKV_ (3 * C_)     // 3072

typedef unsigned short us16;
typedef unsigned int u32;
typedef short bf16x8 __attribute__((ext_vector_type(8)));
typedef float f32x4 __attribute__((ext_vector_type(4)));

__device__ __forceinline__ f32x4 mfma16(bf16x8 a, bf16x8 b, f32x4 c) {
    return __builtin_amdgcn_mfma_f32_16x16x32_bf16(a, b, c, 0, 0, 0);
}

// float -> bf16 round-to-nearest-even
__device__ __forceinline__ us16 f2bf(float f) {
    union { float f; u32 u; } v; v.f = f;
    u32 r = v.u + 0x7fffu + ((v.u >> 16) & 1u);
    return (us16)(r >> 16);
}
__device__ __forceinline__ u32 fbits(float f) {
    union { float f; u32 u; } v; v.f = f; return v.u;
}

// async global->LDS, 16B per lane, lds dest = uniform base + lane*16
typedef __attribute__((address_space(1))) const void as1_cvoid;
typedef __attribute__((address_space(3))) void as3_void;
__device__ __forceinline__ void gload_lds16(const us16* g, us16* l) {
    __builtin_amdgcn_global_load_lds((as1_cvoid*)g, (as3_void*)l, 16, 0, 0);
}

// ---------------------------------------------------------------------------
// fp32 -> bf16 convert (8 elems/thread)
// ---------------------------------------------------------------------------
__global__ __launch_bounds__(256) void cvt_bf16(
    const float* __restrict__ in, us16* __restrict__ out, int n8)
{
    const int i = blockIdx.x * blockDim.x + threadIdx.x;
    if (i >= n8) return;
    const float4 a = ((const float4*)in)[2 * i];
    const float4 b = ((const float4*)in)[2 * i + 1];
    ushort4 lo = { f2bf(a.x), f2bf(a.y), f2bf(a.z), f2bf(a.w) };
    ushort4 hi = { f2bf(b.x), f2bf(b.y), f2bf(b.z), f2bf(b.w) };
    ((ushort4*)out)[2 * i] = lo;
    ((ushort4*)out)[2 * i + 1] = hi;
}

// ---------------------------------------------------------------------------
// W [K][N] fp32  ->  Wt [N][K] bf16   (32x32 LDS tiles)
// ---------------------------------------------------------------------------
__global__ __launch_bounds__(256) void transpose_cvt(
    const float* __restrict__ W, us16* __restrict__ Wt, int K, int N)
{
    __shared__ float tile[32][33];
    const int n0 = blockIdx.x * 32, k0 = blockIdx.y * 32;
    const int t = threadIdx.x;
    {
        const int k = t >> 3, n4 = (t & 7) * 4;
        const float4 v = *(const float4*)(W + (size_t)(k0 + k) * N + n0 + n4);
        tile[k][n4 + 0] = v.x; tile[k][n4 + 1] = v.y;
        tile[k][n4 + 2] = v.z; tile[k][n4 + 3] = v.w;
    }
    __syncthreads();
    {
        const int n = t >> 3, k4 = (t & 7) * 4;
        ushort4 o = { f2bf(tile[k4 + 0][n]), f2bf(tile[k4 + 1][n]),
                      f2bf(tile[k4 + 2][n]), f2bf(tile[k4 + 3][n]) };
        *(ushort4*)(Wt + (size_t)(n0 + n) * K + k0 + k4) = o;
    }
}

// ---------------------------------------------------------------------------
// bf16 MFMA GEMM (m97 structure): C[M][N] = A[M][K] @ Bt[N][K]^T + bias
// 128x128 tile, BK=64, global_load_lds(16B) staging, XOR-swizzled LDS chunks.
// ---------------------------------------------------------------------------
__global__ __launch_bounds__(256) void gemm_bf16(
    const us16* __restrict__ A, const us16* __restrict__ Bt,
    const float* __restrict__ bias, void* __restrict__ Cout,
    int M, int N, int K, int out_bf16)
{
    // staging: 2 x (128 rows x 64 bf16, unpadded; chunk c of row r at slot c^(r&7))
    // epilogue reuses smem as 128 x 136 us16
    __shared__ __align__(16) us16 smem[17408];
    us16* sA = smem;
    us16* sB = smem + 128 * 64;

    const int tid = threadIdx.x;
    const int lane = tid & 63, wave = tid >> 6;
    const int wr = wave >> 1, wc = wave & 1;
    const int cq = lane & 15, quad = lane >> 4;
    const int m0 = blockIdx.y * 128, n0 = blockIdx.x * 128;

    const int srow = lane >> 3;          // 0..7 within 8-row group
    const int schunk = (lane & 7) ^ srow; // logical 16B chunk to fetch

    f32x4 acc[4][4];
    #pragma unroll
    for (int i = 0; i < 4; ++i)
        #pragma unroll
        for (int j = 0; j < 4; ++j)
            acc[i][j] = (f32x4){0.f, 0.f, 0.f, 0.f};

    for (int k0 = 0; k0 < K; k0 += 64) {
        #pragma unroll
        for (int i = 0; i < 4; ++i) {
            const int r0 = wave * 32 + i * 8;
            gload_lds16(A + (size_t)(m0 + r0 + srow) * K + k0 + schunk * 8,
                        sA + r0 * 64);
            gload_lds16(Bt + (size_t)(n0 + r0 + srow) * K + k0 + schunk * 8,
                        sB + r0 * 64);
        }
        __syncthreads();   // drains vmcnt -> staged data visible

        #pragma unroll
        for (int kk = 0; kk < 64; kk += 32) {
            const int cb = kk >> 3;   // chunk base: 0 or 4
            bf16x8 af[4], bfg[4];
            #pragma unroll
            for (int i = 0; i < 4; ++i) {
                const int ra = wr * 64 + i * 16 + cq;
                af[i] = *(const bf16x8*)(sA + ra * 64 + (((cb + quad) ^ (cq & 7)) * 8));
                const int rb = wc * 64 + i * 16 + cq;
                bfg[i] = *(const bf16x8*)(sB + rb * 64 + (((cb + quad) ^ (cq & 7)) * 8));
            }
            #pragma unroll
            for (int mi = 0; mi < 4; ++mi)
                #pragma unroll
                for (int ni = 0; ni < 4; ++ni)
                    acc[mi][ni] = mfma16(af[mi], bfg[ni], acc[mi][ni]);
        }
        __syncthreads();
    }

    // ---- epilogue ----
    if (out_bf16) {
        us16* Cs = smem;   // 128 x 136
        #pragma unroll
        for (int mi = 0; mi < 4; ++mi)
            #pragma unroll
            for (int ni = 0; ni < 4; ++ni) {
                const int n = n0 + wc * 64 + ni * 16 + cq;
                const float bv = bias[n];
                #pragma unroll
                for (int r = 0; r < 4; ++r)
                    Cs[(wr * 64 + mi * 16 + quad * 4 + r) * 136 +
                       wc * 64 + ni * 16 + cq] = f2bf(acc[mi][ni][r] + bv);
            }
        __syncthreads();
        us16* Co = (us16*)Cout;
        #pragma unroll
        for (int p = 0; p < 8; ++p) {
            const int chunk = p * 256 + tid;
            const int r = chunk >> 4, c = (chunk & 15) * 8;
            *(uint4*)(Co + (size_t)(m0 + r) * N + n0 + c) =
                *(const uint4*)(Cs + r * 136 + c);
        }
    } else {
        float* Co = (float*)Cout;
        #pragma unroll
        for (int mi = 0; mi < 4; ++mi)
            #pragma unroll
            for (int ni = 0; ni < 4; ++ni) {
                const int n = n0 + wc * 64 + ni * 16 + cq;
                const float bv = bias[n];
                #pragma unroll
                for (int r = 0; r < 4; ++r)
                    Co[(size_t)(m0 + wr * 64 + mi * 16 + quad * 4 + r) * N + n] =
                        acc[mi][ni][r] + bv;
            }
    }
}

// ---------------------------------------------------------------------------
// MFMA flash attention, S^T formulation + paired q-tiles for load balance.
// Block = (b,h) x pair p: q-tiles qtA=p, qtB=31-p -> exactly 33 compute iters.
// S^T = K Q^T: C-layout row=key(quad*4+r), col=q(cq) -> softmax reductions are
// 15 in-lane ops + 2 shfl_xor. P packed to Ps via 8 ds_write_b32.
// ---------------------------------------------------------------------------
#define SCALE_LOG2E 0.1803368801111729f   // 0.125 * log2(e)

__device__ __forceinline__ void attn_step(
    const us16 (*Ks)[72], const us16 (*Vt)[72], us16 (*Ps)[72],
    const bf16x8* qf, float& m_run, float& l_run, f32x4* o,
    int wave, int cq, int quad, bool diag)
{
    // ---- S^T = K Q^T : 4 key-subtiles x (D=64 -> 2 mfma) ----
    float s[4][4];
    #pragma unroll
    for (int j = 0; j < 4; ++j) {
        const bf16x8 k0 = *(const bf16x8*)(&Ks[j * 16 + cq][quad * 8]);
        const bf16x8 k1 = *(const bf16x8*)(&Ks[j * 16 + cq][32 + quad * 8]);
        f32x4 t = (f32x4){0.f, 0.f, 0.f, 0.f};
        t = mfma16(k0, qf[0], t);
        t = mfma16(k1, qf[1], t);
        #pragma unroll
        for (int r = 0; r < 4; ++r) s[j][r] = t[r] * SCALE_LOG2E;
    }

    // ---- causal mask (diag tile): key j*16+quad*4+r  >  q wave*16+cq ----
    if (diag) {
        const int q = wave * 16 + cq;
        #pragma unroll
        for (int j = 0; j < 4; ++j)
            #pragma unroll
            for (int r = 0; r < 4; ++r)
                if (j * 16 + quad * 4 + r > q) s[j][r] = -1e30f;
    }

    // ---- online softmax over this lane's q-column (16 keys in-lane) ----
    float mx = s[0][0];
    #pragma unroll
    for (int j = 0; j < 4; ++j)
        #pragma unroll
        for (int r = 0; r < 4; ++r) mx = fmaxf(mx, s[j][r]);
    mx = fmaxf(mx, __shfl_xor(mx, 16));
    mx = fmaxf(mx, __shfl_xor(mx, 32));
    const float m_new = fmaxf(m_run, mx);
    const float alpha = exp2f(m_run - m_new);
    float sum = 0.f;
    #pragma unroll
    for (int j = 0; j < 4; ++j)
        #pragma unroll
        for (int r = 0; r < 4; ++r) {
            s[j][r] = exp2f(s[j][r] - m_new);
            sum += s[j][r];
        }
    sum += __shfl_xor(sum, 16);
    sum += __shfl_xor(sum, 32);
    l_run = l_run * alpha + sum;
    m_run = m_new;

    // ---- rescale O (rows q = quad*4+r; alpha lives on lane cq=q) ----
    #pragma unroll
    for (int r = 0; r < 4; ++r) {
        const float ar = __shfl(alpha, 20 * quad + r);
        #pragma unroll
        for (int dt = 0; dt < 4; ++dt) o[dt][r] *= ar;
    }

    // ---- pack P (bf16 truncate) -> Ps[q][key], 8 u32 writes ----
    #pragma unroll
    for (int j = 0; j < 4; ++j) {
        const u32 u0 = (fbits(s[j][1]) & 0xffff0000u) | (fbits(s[j][0]) >> 16);
        const u32 u1 = (fbits(s[j][3]) & 0xffff0000u) | (fbits(s[j][2]) >> 16);
        *(u32*)(&Ps[wave * 16 + cq][j * 16 + quad * 4]) = u0;
        *(u32*)(&Ps[wave * 16 + cq][j * 16 + quad * 4 + 2]) = u1;
    }

    // ---- O += P @ V ----
    const bf16x8 p0 = *(const bf16x8*)(&Ps[wave * 16 + cq][quad * 8]);
    const bf16x8 p1 = *(const bf16x8*)(&Ps[wave * 16 + cq][32 + quad * 8]);
    #pragma unroll
    for (int dt = 0; dt < 4; ++dt) {
        const bf16x8 v0 = *(const bf16x8*)(&Vt[dt * 16 + cq][quad * 8]);
        const bf16x8 v1 = *(const bf16x8*)(&Vt[dt * 16 + cq][32 + quad * 8]);
        o[dt] = mfma16(p0, v0, o[dt]);
        o[dt] = mfma16(p1, v1, o[dt]);
    }
}

__global__ __launch_bounds__(256) void attn_mfma(
    const us16* __restrict__ qkv, us16* __restrict__ y)
{
    __shared__ __align__(16) us16 Ks[64][72];   // K tile [t][d]
    __shared__ __align__(16) us16 Vt[64][72];   // V^T tile [d][t]
    __shared__ __align__(16) us16 Ps[64][72];   // P [q][t] (wave-private rows)

    const int tid = threadIdx.x;
    const int lane = tid & 63, wave = tid >> 6;
    const int cq = lane & 15, quad = lane >> 4;
    const int bh = blockIdx.x;
    const int pr = blockIdx.y;
    const int qtA = pr, qtB = (T_ / 64 - 1) - pr;   // 33 iters per block
    const int b = bh >> 4, h = bh & 15;

    const us16* base = qkv + (size_t)b * T_ * NQKV_ + h * D_;

    // Q fragments (B operand): lane holds Q[q=wave*16+cq][d=c*32+quad*8+..]
    bf16x8 qA[2], qB[2];
    {
        const us16* ra = base + (size_t)(qtA * 64 + wave * 16 + cq) * NQKV_;
        qA[0] = *(const bf16x8*)(ra + quad * 8);
        qA[1] = *(const bf16x8*)(ra + 32 + quad * 8);
        const us16* rb = base + (size_t)(qtB * 64 + wave * 16 + cq) * NQKV_;
        qB[0] = *(const bf16x8*)(rb + quad * 8);
        qB[1] = *(const bf16x8*)(rb + 32 + quad * 8);
    }

    f32x4 oA[4], oB[4];
    #pragma unroll
    for (int j = 0; j < 4; ++j) {
        oA[j] = (f32x4){0.f, 0.f, 0.f, 0.f};
        oB[j] = (f32x4){0.f, 0.f, 0.f, 0.f};
    }
    float mA = -1e30f, lA = 0.f, mB = -1e30f, lB = 0.f;

    const int t2 = tid & 31, dc = tid >> 5;

    for (int kt = 0; kt <= qtB; ++kt) {
        __syncthreads();   // previous iteration's MFMA reads complete
        // ---- stage K [t][d] ----
        #pragma unroll
        for (int p = 0; p < 2; ++p) {
            const int chunk = p * 256 + tid;
            const int r = chunk >> 3, c8 = (chunk & 7) * 8;
            const uint4 v = *(const uint4*)(base + (size_t)(kt * 64 + r) * NQKV_ + C_ + c8);
            *(uint4*)(&Ks[r][c8]) = v;
        }
        // ---- stage V transposed: Vt[d][t], packed pair writes ----
        {
            const us16* vp = base + (size_t)(kt * 64 + 2 * t2) * NQKV_ + 2 * C_ + dc * 8;
            const uint4 u0 = *(const uint4*)vp;
            const uint4 u1 = *(const uint4*)(vp + NQKV_);
            const us16* p0 = (const us16*)&u0;
            const us16* p1 = (const us16*)&u1;
            #pragma unroll
            for (int j = 0; j < 8; ++j) {
                const u32 packed = (u32)p0[j] | ((u32)p1[j] << 16);
                *(u32*)(&Vt[dc * 8 + j][2 * t2]) = packed;
            }
        }
        __syncthreads();

        if (kt <= qtA)
            attn_step(Ks, Vt, Ps, qA, mA, lA, oA, wave, cq, quad, kt == qtA);
        attn_step(Ks, Vt, Ps, qB, mB, lB, oB, wave, cq, quad, kt == qtB);
    }

    // ---- epilogue: normalize, store bf16 (O rows q=quad*4+r) ----
    const float invA = 1.0f / lA, invB = 1.0f / lB;
    #pragma unroll
    for (int r = 0; r < 4; ++r) {
        const float iA = __shfl(invA, 20 * quad + r);
        const float iB = __shfl(invB, 20 * quad + r);
        const int rowA = qtA * 64 + wave * 16 + quad * 4 + r;
        const int rowB = qtB * 64 + wave * 16 + quad * 4 + r;
        #pragma unroll
        for (int dt = 0; dt < 4; ++dt) {
            y[(size_t)(b * T_ + rowA) * C_ + h * D_ + dt * 16 + cq] = f2bf(oA[dt][r] * iA);
            y[(size_t)(b * T_ + rowB) * C_ + h * D_ + dt * 16 + cq] = f2bf(oB[dt][r] * iB);
        }
    }
}

// ---------------------------------------------------------------------------
extern "C" void kernel_launch(void* const* d_in, const int* in_sizes, int n_in,
                              void* d_out, int out_size, void* d_ws, size_t ws_size,
                              hipStream_t stream)
{
    const float* x  = (const float*)d_in[0];   // [B,T,C]
    const float* aw = (const float*)d_in[1];   // [C,3C]
    const float* ab = (const float*)d_in[2];   // [3C]
    const float* pw = (const float*)d_in[3];   // [C,C]
    const float* pb = (const float*)d_in[4];   // [C]
    float* out = (float*)d_out;                // [B,T,C] fp32

    us16* xb   = (us16*)d_ws;                        // [4096][1024]
    us16* awT  = xb  + (size_t)M_ * C_;              // [3072][1024]
    us16* pwT  = awT + (size_t)NQKV_ * C_;           // [1024][1024]
    us16* qkvb = pwT + (size_t)C_ * C_;              // [4096][3072]
    us16* yb   = qkvb + (size_t)M_ * NQKV_;          // [4096][1024]

    // pre-pass: bf16 conversions
    cvt_bf16<<<(M_ * C_ / 8 + 255) / 256, 256, 0, stream>>>(x, xb, M_ * C_ / 8);
    transpose_cvt<<<dim3(NQKV_ / 32, C_ / 32), 256, 0, stream>>>(aw, awT, C_, NQKV_);
    transpose_cvt<<<dim3(C_ / 32, C_ / 32), 256, 0, stream>>>(pw, pwT, C_, C_);

    // 1) qkv = x @ c_attn_w + b   (bf16 out)
    gemm_bf16<<<dim3(NQKV_ / 128, M_ / 128), 256, 0, stream>>>(
        xb, awT, ab, qkvb, M_, NQKV_, C_, 1);

    // 2) flash attention (MFMA, paired q-tiles)
    attn_mfma<<<dim3(B_ * H_, T_ / 128), 256, 0, stream>>>(qkvb, yb);

    // 3) out = y @ c_proj_w + b   (fp32 out)
    gemm_bf16<<<dim3(C_ / 128, M_ / 128), 256, 0, stream>>>(
        yb, pwT, pb, out, M_, C_, C_, 0);
}